// Round 11
// baseline (670.374 us; speedup 1.0000x reference)
//
#include <hip/hip_runtime.h>
#include <math.h>

// Sizes fixed by the reference: B=512, T=1024, D_IN=D_OUT=64, H=256.
#define HDIM 256
#define DDIM 64
#define BROWS 512
#define TSTEPS 1024
// Augmented rows: 65 weight rows (t-row + 64 state rows) + 1 bias row.
#define AROWS 66

typedef float f32x2 __attribute__((ext_vector_type(2)));
typedef float f32x4 __attribute__((ext_vector_type(4)));

// ---- Setup: compose the linear MLP into one 66x64 affine map ----
__global__ void compose1(const float* __restrict__ W0, const float* __restrict__ b0,
                         const float* __restrict__ W1, const float* __restrict__ b1,
                         float* __restrict__ out1) {
    int r = blockIdx.x;    // 0..65
    int c = threadIdx.x;   // 0..255
    const float* arow = (r < 65) ? (W0 + r * HDIM) : b0;
    float acc = (r == 65) ? b1[c] : 0.0f;
    for (int h = 0; h < HDIM; ++h)
        acc = fmaf(arow[h], W1[h * HDIM + c], acc);
    out1[r * HDIM + c] = acc;
}

__global__ void compose2(const float* __restrict__ in1,
                         const float* __restrict__ W2, const float* __restrict__ b2,
                         float* __restrict__ out2) {
    int r = blockIdx.x, c = threadIdx.x;
    const float* arow = in1 + r * HDIM;
    float acc = (r == 65) ? b2[c] : 0.0f;
    for (int h = 0; h < HDIM; ++h)
        acc = fmaf(arow[h], W2[h * HDIM + c], acc);
    out2[r * HDIM + c] = acc;
}

__global__ void compose3(const float* __restrict__ in2,
                         const float* __restrict__ W3, const float* __restrict__ b3,
                         float* __restrict__ out3) {
    int r = blockIdx.x, c = threadIdx.x;   // c 0..63
    const float* arow = in2 + r * HDIM;
    float acc = (r == 65) ? b3[c] : 0.0f;
    for (int h = 0; h < HDIM; ++h)
        acc = fmaf(arow[h], W3[h * DDIM + c], acc);
    out3[r * DDIM + c] = acc;
}

// Packed 2xf32 FMA: acc.lo += a.lo*b.lo; acc.hi += a.hi*b.hi  (VOP3P, CDNA)
__device__ __forceinline__ void pkfma(f32x2& acc, f32x2 a, f32x2 b) {
    asm("v_pk_fma_f32 %0, %1, %2, %0" : "+v"(acc) : "v"(a), "v"(b));
}

// ---- Main scan: one wave per TWO batch rows, lane = output dim ----
// y_new[d] = y[d] + factor_k * tanh(b_eff[d] + t_k*w_t[d] + sum_j y[j]*Weff[j][d])
//
// r7 (best, 643 cyc/step) was ~210 cyc issue + ~430 cyc stall (LDS
// turnaround, DS return latency, accumulator deps, TRANS tail) — a lone
// wave has nothing to fill the stalls. This round: 2 independent rows per
// wave, SAME r7 structure. The rows share Wp (weights), the LDS turnaround
// and DS drain are paid once per step for both rows, and the rows'
// pk_fma/reduce/tanh chains interleave in the issue slots the other row
// stalls in. r5's failed 2-row attempt lacked (64,1) (AGPR parking, ~40
// free VGPRs serializing 32 read latencies) and used scalar FMAs; both
// fixed here (~230 VGPRs needed, budget 512; pk_fma halves the math).
__launch_bounds__(64, 1)
__global__ void fode_scan(const float* __restrict__ x, const float* __restrict__ t,
                          const float* __restrict__ Weff,   // 66 x 64 composed
                          float* __restrict__ out) {
    const int bA = blockIdx.x * 2;      // rows bA, bA+1
    const int d  = threadIdx.x;         // 0..63

    __shared__ float  ylds[2 * DDIM];   // [0..63]=row A, [64..127]=row B
    __shared__ float2 plds[TSTEPS];     // (t_k, factor_k); entry TSTEPS-1 unused

    const float invG = 0.56418958354775628695f;  // 1/Gamma(0.5)

    // Stage per-step params: coalesced, once per block (t is 4 KB, L2-hot).
    for (int i = d; i < TSTEPS - 1; i += DDIM) {
        float t0 = t[i];
        float t1 = t[i + 1];
        plds[i] = make_float2(t0, sqrtf(t1 - t0) * invG);
    }

    // W column for this lane, as j-pairs: Wp[c] = (W[2c][d], W[2c+1][d]).
    // Shared by both rows.
    f32x2 Wp[DDIM / 2];
#pragma unroll
    for (int c = 0; c < DDIM / 2; ++c) {
        Wp[c].x = Weff[(1 + 2 * c) * DDIM + d];
        Wp[c].y = Weff[(2 + 2 * c) * DDIM + d];
    }
    const float wt   = Weff[d];                 // t-coefficient row
    const float bias = Weff[65 * DDIM + d];     // folded bias row

    float ya = x[bA * DDIM + d];
    float yb = x[(bA + 1) * DDIM + d];
    float* opA = out + (size_t)bA * TSTEPS * DDIM + d;
    float* opB = opA + (size_t)TSTEPS * DDIM;
    *opA = ya;                                   // solution[:,0,:] = x
    *opB = yb;
    ylds[d] = ya;
    ylds[DDIM + d] = yb;
    asm volatile("" ::: "memory");               // writes visible to loop reads

    float2 prm = plds[0];                        // same-wave DS: in-order

    for (int k = 0; k < TSTEPS - 1; ++k) {
        // Issue both rows' broadcast reads up front (same-address across the
        // wave = conflict-free). Counted lgkm waits let row A's consumption
        // start while row B's reads are still in flight.
        f32x4 va[16], vb[16];
#pragma unroll
        for (int c = 0; c < 16; ++c)
            va[c] = *reinterpret_cast<const f32x4*>(&ylds[c * 4]);
#pragma unroll
        for (int c = 0; c < 16; ++c)
            vb[c] = *reinterpret_cast<const f32x4*>(&ylds[DDIM + c * 4]);

        float2 prm_next = plds[k + 1];           // prefetch; garbage at last iter, unused
        float base = fmaf(prm.x, wt, bias);      // t-term + bias, shared by both rows

        f32x2 aA0 = {base, 0.f}, aA1 = {0.f, 0.f};
        f32x2 aB0 = {base, 0.f}, aB1 = {0.f, 0.f};
#pragma unroll
        for (int c = 0; c < 16; ++c) {
            f32x2 lo = __builtin_shufflevector(va[c], va[c], 0, 1);
            f32x2 hi = __builtin_shufflevector(va[c], va[c], 2, 3);
            pkfma(aA0, lo, Wp[2 * c + 0]);
            pkfma(aA1, hi, Wp[2 * c + 1]);
        }
#pragma unroll
        for (int c = 0; c < 16; ++c) {
            f32x2 lo = __builtin_shufflevector(vb[c], vb[c], 0, 1);
            f32x2 hi = __builtin_shufflevector(vb[c], vb[c], 2, 3);
            pkfma(aB0, lo, Wp[2 * c + 0]);
            pkfma(aB1, hi, Wp[2 * c + 1]);
        }
        f32x2 rA = aA0 + aA1;                    // v_pk_add_f32
        f32x2 rB = aB0 + aB1;
        float sA = rA.x + rA.y;
        float sB = rB.x + rB.y;

        // tanh(s) = 1 - 2/(exp(2s)+1); the two rows' TRANS chains interleave.
        float eA  = __builtin_amdgcn_exp2f(sA * 2.88539008177792681472f); // 2*log2(e)
        float eB  = __builtin_amdgcn_exp2f(sB * 2.88539008177792681472f);
        float thA = fmaf(-2.0f, __builtin_amdgcn_rcpf(eA + 1.0f), 1.0f);
        float thB = fmaf(-2.0f, __builtin_amdgcn_rcpf(eB + 1.0f), 1.0f);

        ya = fmaf(prm.y, thA, ya);
        yb = fmaf(prm.y, thB, yb);

        ylds[d] = ya;                             // next iter's inputs (in-order DS)
        ylds[DDIM + d] = yb;
        asm volatile("" ::: "memory");            // fence before next iter's reads
        opA += DDIM;
        opB += DDIM;
        *opA = ya;                                // fire-and-forget, never waited
        *opB = yb;
        prm = prm_next;
    }
}

extern "C" void kernel_launch(void* const* d_in, const int* in_sizes, int n_in,
                              void* d_out, int out_size, void* d_ws, size_t ws_size,
                              hipStream_t stream) {
    const float* x  = (const float*)d_in[0];
    const float* t  = (const float*)d_in[1];
    const float* W0 = (const float*)d_in[2];
    const float* b0 = (const float*)d_in[3];
    const float* W1 = (const float*)d_in[4];
    const float* b1 = (const float*)d_in[5];
    const float* W2 = (const float*)d_in[6];
    const float* b2 = (const float*)d_in[7];
    const float* W3 = (const float*)d_in[8];
    const float* b3 = (const float*)d_in[9];
    float* out = (float*)d_out;

    float* buf1 = (float*)d_ws;            // 66*256 floats
    float* buf2 = buf1 + AROWS * HDIM;     // 66*256 floats
    float* buf3 = buf2 + AROWS * HDIM;     // 66*64 floats

    compose1<<<AROWS, HDIM, 0, stream>>>(W0, b0, W1, b1, buf1);
    compose2<<<AROWS, HDIM, 0, stream>>>(buf1, W2, b2, buf2);
    compose3<<<AROWS, DDIM, 0, stream>>>(buf2, W3, b3, buf3);
    fode_scan<<<BROWS / 2, DDIM, 0, stream>>>(x, t, buf3, out);
}

// Round 12
// 273.381 us; speedup vs baseline: 2.4522x; 2.4522x over previous
//
#include <hip/hip_runtime.h>
#include <math.h>

// Sizes fixed by the reference: B=512, T=1024, D_IN=D_OUT=64, H=256.
#define HDIM 256
#define DDIM 64
#define BROWS 512
#define TSTEPS 1024
// Augmented rows: 65 weight rows (t-row + 64 state rows) + 1 bias row.
#define AROWS 66

typedef float f32x2 __attribute__((ext_vector_type(2)));
typedef float f32x4 __attribute__((ext_vector_type(4)));

// ---- Setup: compose the linear MLP into one 66x64 affine map ----
__global__ void compose1(const float* __restrict__ W0, const float* __restrict__ b0,
                         const float* __restrict__ W1, const float* __restrict__ b1,
                         float* __restrict__ out1) {
    int r = blockIdx.x;    // 0..65
    int c = threadIdx.x;   // 0..255
    const float* arow = (r < 65) ? (W0 + r * HDIM) : b0;
    float acc = (r == 65) ? b1[c] : 0.0f;
    for (int h = 0; h < HDIM; ++h)
        acc = fmaf(arow[h], W1[h * HDIM + c], acc);
    out1[r * HDIM + c] = acc;
}

__global__ void compose2(const float* __restrict__ in1,
                         const float* __restrict__ W2, const float* __restrict__ b2,
                         float* __restrict__ out2) {
    int r = blockIdx.x, c = threadIdx.x;
    const float* arow = in1 + r * HDIM;
    float acc = (r == 65) ? b2[c] : 0.0f;
    for (int h = 0; h < HDIM; ++h)
        acc = fmaf(arow[h], W2[h * HDIM + c], acc);
    out2[r * HDIM + c] = acc;
}

__global__ void compose3(const float* __restrict__ in2,
                         const float* __restrict__ W3, const float* __restrict__ b3,
                         float* __restrict__ out3) {
    int r = blockIdx.x, c = threadIdx.x;   // c 0..63
    const float* arow = in2 + r * HDIM;
    float acc = (r == 65) ? b3[c] : 0.0f;
    for (int h = 0; h < HDIM; ++h)
        acc = fmaf(arow[h], W3[h * DDIM + c], acc);
    out3[r * DDIM + c] = acc;
}

// Packed 2xf32 FMA: acc.lo += a.lo*b.lo; acc.hi += a.hi*b.hi  (VOP3P, CDNA)
__device__ __forceinline__ void pkfma(f32x2& acc, f32x2 a, f32x2 b) {
    asm("v_pk_fma_f32 %0, %1, %2, %0" : "+v"(acc) : "v"(a), "v"(b));
}

// ---- Main scan: one wave per batch row, lane = output dim ----
// y_new[d] = y[d] + factor_k * tanh(b_eff[d] + t_k*w_t[d] + sum_j y[j]*Weff[j][d])
//
// Rounds 7-11 diagnosis: the allocator never grants >~52 arch VGPRs
// (arrays get parked in AGPRs / reads serialized read-wait-park), so the
// 16-deep LDS broadcast pipeline I keep writing gets executed as ~8 exposed
// ~100-cyc DS waits per step. Fix: inline-asm ds_read_b128 with "=&v"
// outputs FORCES 16 live arch-VGPR quads; all reads issue back-to-back,
// one lgkmcnt(0) drain, then 32 v_pk_fma_f32. ylds is touched ONLY by asm
// (volatile-asm ordering + in-order DS = correctness, no barriers).
__launch_bounds__(64, 1) __attribute__((amdgpu_waves_per_eu(1)))
__global__ void fode_scan(const float* __restrict__ x, const float* __restrict__ t,
                          const float* __restrict__ Weff,   // 66 x 64 composed
                          float* __restrict__ out) {
    const int b = blockIdx.x;
    const int d = threadIdx.x;   // 0..63

    __shared__ __align__(16) float ylds[DDIM];
    __shared__ float2 plds[TSTEPS];   // (t_k, factor_k); entry TSTEPS-1 unused

    const float invG = 0.56418958354775628695f;  // 1/Gamma(0.5)

    // Stage per-step params: coalesced, once per block (t is 4 KB, L2-hot).
    for (int i = d; i < TSTEPS - 1; i += DDIM) {
        float t0 = t[i];
        float t1 = t[i + 1];
        plds[i] = make_float2(t0, sqrtf(t1 - t0) * invG);
    }

    // W column for this lane, as j-pairs: Wp[c] = (W[2c][d], W[2c+1][d])
    f32x2 Wp[DDIM / 2];
#pragma unroll
    for (int c = 0; c < DDIM / 2; ++c) {
        Wp[c].x = Weff[(1 + 2 * c) * DDIM + d];
        Wp[c].y = Weff[(2 + 2 * c) * DDIM + d];
    }
    const float wt   = Weff[d];                 // t-coefficient row
    const float bias = Weff[65 * DDIM + d];     // folded bias row

    const unsigned ybase = (unsigned)(uintptr_t)&ylds[0];  // LDS byte offset
    const unsigned waddr = ybase + 4u * (unsigned)d;

    float y = x[b * DDIM + d];
    float* op = out + (size_t)b * TSTEPS * DDIM + d;
    *op = y;                                     // solution[:,0,:] = x
    asm volatile("ds_write_b32 %0, %1" :: "v"(waddr), "v"(y));

    float2 prm = plds[0];                        // compiler-managed DS (own waits)

    for (int k = 0; k < TSTEPS - 1; ++k) {
        // 16 broadcast reads, all in flight at once (forced arch-VGPR quads).
        f32x4 v0, v1, v2, v3, v4, v5, v6, v7, v8, v9, v10, v11, v12, v13, v14, v15;
        asm volatile(
            "ds_read_b128 %[o0],  %[a] offset:0\n\t"
            "ds_read_b128 %[o1],  %[a] offset:16\n\t"
            "ds_read_b128 %[o2],  %[a] offset:32\n\t"
            "ds_read_b128 %[o3],  %[a] offset:48\n\t"
            "ds_read_b128 %[o4],  %[a] offset:64\n\t"
            "ds_read_b128 %[o5],  %[a] offset:80\n\t"
            "ds_read_b128 %[o6],  %[a] offset:96\n\t"
            "ds_read_b128 %[o7],  %[a] offset:112\n\t"
            "ds_read_b128 %[o8],  %[a] offset:128\n\t"
            "ds_read_b128 %[o9],  %[a] offset:144\n\t"
            "ds_read_b128 %[o10], %[a] offset:160\n\t"
            "ds_read_b128 %[o11], %[a] offset:176\n\t"
            "ds_read_b128 %[o12], %[a] offset:192\n\t"
            "ds_read_b128 %[o13], %[a] offset:208\n\t"
            "ds_read_b128 %[o14], %[a] offset:224\n\t"
            "ds_read_b128 %[o15], %[a] offset:240"
            : [o0] "=&v"(v0), [o1] "=&v"(v1), [o2] "=&v"(v2), [o3] "=&v"(v3),
              [o4] "=&v"(v4), [o5] "=&v"(v5), [o6] "=&v"(v6), [o7] "=&v"(v7),
              [o8] "=&v"(v8), [o9] "=&v"(v9), [o10] "=&v"(v10), [o11] "=&v"(v11),
              [o12] "=&v"(v12), [o13] "=&v"(v13), [o14] "=&v"(v14), [o15] "=&v"(v15)
            : [a] "v"(ybase));

        float2 prm_next = plds[k + 1];           // prefetch; garbage at last iter, unused
        float base = fmaf(prm.x, wt, bias);      // t-term + bias (overlaps DS latency)

        asm volatile("s_waitcnt lgkmcnt(0)" ::: "memory");
        __builtin_amdgcn_sched_barrier(0);       // rule #18: no hoisting past the wait

        f32x2 acc0 = {base, 0.f}, acc1 = {0.f, 0.f};
        f32x2 acc2 = {0.f, 0.f},  acc3 = {0.f, 0.f};
        const f32x4 vv[16] = {v0, v1, v2, v3, v4, v5, v6, v7,
                              v8, v9, v10, v11, v12, v13, v14, v15};
#pragma unroll
        for (int c = 0; c < 16; c += 2) {
            f32x2 lo0 = __builtin_shufflevector(vv[c], vv[c], 0, 1);
            f32x2 hi0 = __builtin_shufflevector(vv[c], vv[c], 2, 3);
            f32x2 lo1 = __builtin_shufflevector(vv[c + 1], vv[c + 1], 0, 1);
            f32x2 hi1 = __builtin_shufflevector(vv[c + 1], vv[c + 1], 2, 3);
            pkfma(acc0, lo0, Wp[2 * c + 0]);
            pkfma(acc1, hi0, Wp[2 * c + 1]);
            pkfma(acc2, lo1, Wp[2 * c + 2]);
            pkfma(acc3, hi1, Wp[2 * c + 3]);
        }
        f32x2 rA = acc0 + acc1;                  // v_pk_add_f32
        f32x2 rB = acc2 + acc3;
        f32x2 rT = rA + rB;
        float s = rT.x + rT.y;

        // tanh(s) = 1 - 2/(exp(2s)+1), via raw v_exp_f32 + v_rcp_f32
        float e  = __builtin_amdgcn_exp2f(s * 2.88539008177792681472f); // 2*log2(e)
        float th = fmaf(-2.0f, __builtin_amdgcn_rcpf(e + 1.0f), 1.0f);

        y = fmaf(prm.y, th, y);

        asm volatile("ds_write_b32 %0, %1" :: "v"(waddr), "v"(y));  // next iter's input
        op += DDIM;
        *op = y;                                  // fire-and-forget, never waited
        prm = prm_next;
    }
}

extern "C" void kernel_launch(void* const* d_in, const int* in_sizes, int n_in,
                              void* d_out, int out_size, void* d_ws, size_t ws_size,
                              hipStream_t stream) {
    const float* x  = (const float*)d_in[0];
    const float* t  = (const float*)d_in[1];
    const float* W0 = (const float*)d_in[2];
    const float* b0 = (const float*)d_in[3];
    const float* W1 = (const float*)d_in[4];
    const float* b1 = (const float*)d_in[5];
    const float* W2 = (const float*)d_in[6];
    const float* b2 = (const float*)d_in[7];
    const float* W3 = (const float*)d_in[8];
    const float* b3 = (const float*)d_in[9];
    float* out = (float*)d_out;

    float* buf1 = (float*)d_ws;            // 66*256 floats
    float* buf2 = buf1 + AROWS * HDIM;     // 66*256 floats
    float* buf3 = buf2 + AROWS * HDIM;     // 66*64 floats

    compose1<<<AROWS, HDIM, 0, stream>>>(W0, b0, W1, b1, buf1);
    compose2<<<AROWS, HDIM, 0, stream>>>(buf1, W2, b2, buf2);
    compose3<<<AROWS, DDIM, 0, stream>>>(buf2, W3, b3, buf3);
    fode_scan<<<BROWS, DDIM, 0, stream>>>(x, t, buf3, out);
}

// Round 13
// 272.957 us; speedup vs baseline: 2.4560x; 1.0016x over previous
//
#include <hip/hip_runtime.h>
#include <math.h>

// Sizes fixed by the reference: B=512, T=1024, D_IN=D_OUT=64, H=256.
#define HDIM 256
#define DDIM 64
#define BROWS 512
#define TSTEPS 1024
// Augmented rows: 65 weight rows (t-row + 64 state rows) + 1 bias row.
#define AROWS 66

typedef float f32x2 __attribute__((ext_vector_type(2)));
typedef float f32x4 __attribute__((ext_vector_type(4)));

// ---- Setup: compose the linear MLP into one 66x64 affine map ----
__global__ void compose1(const float* __restrict__ W0, const float* __restrict__ b0,
                         const float* __restrict__ W1, const float* __restrict__ b1,
                         float* __restrict__ out1) {
    int r = blockIdx.x;    // 0..65
    int c = threadIdx.x;   // 0..255
    const float* arow = (r < 65) ? (W0 + r * HDIM) : b0;
    float acc = (r == 65) ? b1[c] : 0.0f;
    for (int h = 0; h < HDIM; ++h)
        acc = fmaf(arow[h], W1[h * HDIM + c], acc);
    out1[r * HDIM + c] = acc;
}

__global__ void compose2(const float* __restrict__ in1,
                         const float* __restrict__ W2, const float* __restrict__ b2,
                         float* __restrict__ out2) {
    int r = blockIdx.x, c = threadIdx.x;
    const float* arow = in1 + r * HDIM;
    float acc = (r == 65) ? b2[c] : 0.0f;
    for (int h = 0; h < HDIM; ++h)
        acc = fmaf(arow[h], W2[h * HDIM + c], acc);
    out2[r * HDIM + c] = acc;
}

__global__ void compose3(const float* __restrict__ in2,
                         const float* __restrict__ W3, const float* __restrict__ b3,
                         float* __restrict__ out3) {
    int r = blockIdx.x, c = threadIdx.x;   // c 0..63
    const float* arow = in2 + r * HDIM;
    float acc = (r == 65) ? b3[c] : 0.0f;
    for (int h = 0; h < HDIM; ++h)
        acc = fmaf(arow[h], W3[h * DDIM + c], acc);
    out3[r * DDIM + c] = acc;
}

// Packed 2xf32 FMA: acc.lo += a.lo*b.lo; acc.hi += a.hi*b.hi  (VOP3P, CDNA)
__device__ __forceinline__ void pkfma(f32x2& acc, f32x2 a, f32x2 b) {
    asm("v_pk_fma_f32 %0, %1, %2, %0" : "+v"(acc) : "v"(a), "v"(b));
}

// ---- Main scan: one wave per batch row, lane = output dim ----
// y_new[d] = y[d] + factor_k * tanh(b_eff[d] + t_k*w_t[d] + sum_j y[j]*Weff[j][d])
//
// r12 post-mortem: wall/step = fixed serial latency + instr count x ~2.
// r12's fixed part (~470cyc) was dominated by the single lgkmcnt(0) drain:
// no pkfma until write(~120) + ALL 17 DS ops drained (~140). This round:
// counted lgkmcnt waits (T4) — all loop DS ops are inline asm (exact
// counts), quads consumed in groups of 4 as they retire (DS is in-order),
// sched_barrier(0) after every wait (rule #18). First pkfma at ~write+130.
// Also: Wp/wt/bias pre-scaled by 2*log2(e), deleting the dependent mul
// before exp2. AGPR parking by the allocator is fine (unified file, VALU
// reads AGPRs directly) — r11's theory was wrong, no reg forcing needed.
__launch_bounds__(64, 1)
__global__ void fode_scan(const float* __restrict__ x, const float* __restrict__ t,
                          const float* __restrict__ Weff,   // 66 x 64 composed
                          float* __restrict__ out) {
    const int b = blockIdx.x;
    const int d = threadIdx.x;   // 0..63

    __shared__ __align__(16) float ylds[DDIM];
    __shared__ __align__(8) float2 plds[TSTEPS];  // (t_k, factor_k); last entry unused

    const float invG = 0.56418958354775628695f;   // 1/Gamma(0.5)
    const float K2L = 2.88539008177792681472f;    // 2*log2(e)

    // Stage per-step params: coalesced, once per block (t is 4 KB, L2-hot).
    for (int i = d; i < TSTEPS - 1; i += DDIM) {
        float t0 = t[i];
        float t1 = t[i + 1];
        plds[i] = make_float2(t0, sqrtf(t1 - t0) * invG);
    }

    // W column for this lane, as j-pairs, PRE-SCALED by 2*log2(e):
    // the dot then directly yields the exp2 argument.
    f32x2 Wp[DDIM / 2];
#pragma unroll
    for (int c = 0; c < DDIM / 2; ++c) {
        Wp[c].x = K2L * Weff[(1 + 2 * c) * DDIM + d];
        Wp[c].y = K2L * Weff[(2 + 2 * c) * DDIM + d];
    }
    const float wts   = K2L * Weff[d];            // scaled t-coefficient
    const float biass = K2L * Weff[65 * DDIM + d];// scaled folded bias

    const unsigned ybase = (unsigned)(uintptr_t)&ylds[0];
    const unsigned waddr = ybase + 4u * (unsigned)d;
    const unsigned pbase = (unsigned)(uintptr_t)&plds[0];

    float y = x[b * DDIM + d];
    float* op = out + (size_t)b * TSTEPS * DDIM + d;
    *op = y;                                      // solution[:,0,:] = x
    asm volatile("ds_write_b32 %0, %1" :: "v"(waddr), "v"(y));

    f32x2 prm;                                    // (t_k, factor_k) current
    prm.x = plds[0].x;
    prm.y = plds[0].y;

    for (int k = 0; k < TSTEPS - 1; ++k) {
        // ---- issue ALL loop DS ops (asm => exact lgkm counts) ----
        unsigned paddr = pbase + 8u * (unsigned)(k + 1);
        f32x2 prmn;
        asm volatile("ds_read_b64 %0, %1" : "=&v"(prmn) : "v"(paddr));

        f32x4 v0, v1, v2, v3, v4, v5, v6, v7, v8, v9, v10, v11, v12, v13, v14, v15;
        asm volatile(
            "ds_read_b128 %[o0],  %[a] offset:0\n\t"
            "ds_read_b128 %[o1],  %[a] offset:16\n\t"
            "ds_read_b128 %[o2],  %[a] offset:32\n\t"
            "ds_read_b128 %[o3],  %[a] offset:48\n\t"
            "ds_read_b128 %[o4],  %[a] offset:64\n\t"
            "ds_read_b128 %[o5],  %[a] offset:80\n\t"
            "ds_read_b128 %[o6],  %[a] offset:96\n\t"
            "ds_read_b128 %[o7],  %[a] offset:112\n\t"
            "ds_read_b128 %[o8],  %[a] offset:128\n\t"
            "ds_read_b128 %[o9],  %[a] offset:144\n\t"
            "ds_read_b128 %[o10], %[a] offset:160\n\t"
            "ds_read_b128 %[o11], %[a] offset:176\n\t"
            "ds_read_b128 %[o12], %[a] offset:192\n\t"
            "ds_read_b128 %[o13], %[a] offset:208\n\t"
            "ds_read_b128 %[o14], %[a] offset:224\n\t"
            "ds_read_b128 %[o15], %[a] offset:240"
            : [o0] "=&v"(v0), [o1] "=&v"(v1), [o2] "=&v"(v2), [o3] "=&v"(v3),
              [o4] "=&v"(v4), [o5] "=&v"(v5), [o6] "=&v"(v6), [o7] "=&v"(v7),
              [o8] "=&v"(v8), [o9] "=&v"(v9), [o10] "=&v"(v10), [o11] "=&v"(v11),
              [o12] "=&v"(v12), [o13] "=&v"(v13), [o14] "=&v"(v14), [o15] "=&v"(v15)
            : [a] "v"(ybase));

        // Outstanding now (oldest first): y-write, prm-read, v0..v15  (18).
        float base = fmaf(prm.x, wts, biass);     // overlaps DS latency

        f32x2 acc0 = {base, 0.f}, acc1 = {0.f, 0.f};
        f32x2 acc2 = {0.f, 0.f},  acc3 = {0.f, 0.f};

#define QUAD(vq, q, cA, cB)                                            \
        {                                                              \
            f32x2 lo = __builtin_shufflevector(vq, vq, 0, 1);          \
            f32x2 hi = __builtin_shufflevector(vq, vq, 2, 3);          \
            pkfma(cA, lo, Wp[2 * (q) + 0]);                            \
            pkfma(cB, hi, Wp[2 * (q) + 1]);                            \
        }

        // DS retires in order: count<=12 => write,prm,v0..v3 done. Etc.
        asm volatile("s_waitcnt lgkmcnt(12)" ::: "memory");
        __builtin_amdgcn_sched_barrier(0);
        QUAD(v0, 0, acc0, acc1) QUAD(v1, 1, acc2, acc3)
        QUAD(v2, 2, acc0, acc1) QUAD(v3, 3, acc2, acc3)

        asm volatile("s_waitcnt lgkmcnt(8)" ::: "memory");
        __builtin_amdgcn_sched_barrier(0);
        QUAD(v4, 4, acc0, acc1) QUAD(v5, 5, acc2, acc3)
        QUAD(v6, 6, acc0, acc1) QUAD(v7, 7, acc2, acc3)

        asm volatile("s_waitcnt lgkmcnt(4)" ::: "memory");
        __builtin_amdgcn_sched_barrier(0);
        QUAD(v8, 8, acc0, acc1)  QUAD(v9, 9, acc2, acc3)
        QUAD(v10, 10, acc0, acc1) QUAD(v11, 11, acc2, acc3)

        asm volatile("s_waitcnt lgkmcnt(0)" ::: "memory");
        __builtin_amdgcn_sched_barrier(0);
        QUAD(v12, 12, acc0, acc1) QUAD(v13, 13, acc2, acc3)
        QUAD(v14, 14, acc0, acc1) QUAD(v15, 15, acc2, acc3)
#undef QUAD

        f32x2 rA = acc0 + acc1;                   // v_pk_add_f32
        f32x2 rB = acc2 + acc3;
        f32x2 rT = rA + rB;
        float sp = rT.x + rT.y;                   // already scaled by 2*log2(e)

        // tanh = 1 - 2/(exp2(sp)+1)
        float e  = __builtin_amdgcn_exp2f(sp);
        float th = fmaf(-2.0f, __builtin_amdgcn_rcpf(e + 1.0f), 1.0f);

        y = fmaf(prm.y, th, y);

        asm volatile("ds_write_b32 %0, %1" :: "v"(waddr), "v"(y)); // next iter input
        op += DDIM;
        *op = y;                                  // fire-and-forget, never waited
        prm = prmn;
    }
}

extern "C" void kernel_launch(void* const* d_in, const int* in_sizes, int n_in,
                              void* d_out, int out_size, void* d_ws, size_t ws_size,
                              hipStream_t stream) {
    const float* x  = (const float*)d_in[0];
    const float* t  = (const float*)d_in[1];
    const float* W0 = (const float*)d_in[2];
    const float* b0 = (const float*)d_in[3];
    const float* W1 = (const float*)d_in[4];
    const float* b1 = (const float*)d_in[5];
    const float* W2 = (const float*)d_in[6];
    const float* b2 = (const float*)d_in[7];
    const float* W3 = (const float*)d_in[8];
    const float* b3 = (const float*)d_in[9];
    float* out = (float*)d_out;

    float* buf1 = (float*)d_ws;            // 66*256 floats
    float* buf2 = buf1 + AROWS * HDIM;     // 66*256 floats
    float* buf3 = buf2 + AROWS * HDIM;     // 66*64 floats

    compose1<<<AROWS, HDIM, 0, stream>>>(W0, b0, W1, b1, buf1);
    compose2<<<AROWS, HDIM, 0, stream>>>(buf1, W2, b2, buf2);
    compose3<<<AROWS, DDIM, 0, stream>>>(buf2, W3, b3, buf3);
    fode_scan<<<BROWS, DDIM, 0, stream>>>(x, t, buf3, out);
}

// Round 14
// 237.528 us; speedup vs baseline: 2.8223x; 1.1492x over previous
//
#include <hip/hip_runtime.h>
#include <math.h>

// Sizes fixed by the reference: B=512, T=1024, D_IN=D_OUT=64, H=256.
#define HDIM 256
#define DDIM 64
#define BROWS 512
#define TSTEPS 1024
// Augmented rows: 65 weight rows (t-row + 64 state rows) + 1 bias row.
#define AROWS 66

typedef float f32x2 __attribute__((ext_vector_type(2)));
typedef float f32x4 __attribute__((ext_vector_type(4)));

// ---- Setup: compose the linear MLP into one 66x64 affine map ----
__global__ void compose1(const float* __restrict__ W0, const float* __restrict__ b0,
                         const float* __restrict__ W1, const float* __restrict__ b1,
                         float* __restrict__ out1) {
    int r = blockIdx.x;    // 0..65
    int c = threadIdx.x;   // 0..255
    const float* arow = (r < 65) ? (W0 + r * HDIM) : b0;
    float acc = (r == 65) ? b1[c] : 0.0f;
    for (int h = 0; h < HDIM; ++h)
        acc = fmaf(arow[h], W1[h * HDIM + c], acc);
    out1[r * HDIM + c] = acc;
}

__global__ void compose2(const float* __restrict__ in1,
                         const float* __restrict__ W2, const float* __restrict__ b2,
                         float* __restrict__ out2) {
    int r = blockIdx.x, c = threadIdx.x;
    const float* arow = in1 + r * HDIM;
    float acc = (r == 65) ? b2[c] : 0.0f;
    for (int h = 0; h < HDIM; ++h)
        acc = fmaf(arow[h], W2[h * HDIM + c], acc);
    out2[r * HDIM + c] = acc;
}

__global__ void compose3(const float* __restrict__ in2,
                         const float* __restrict__ W3, const float* __restrict__ b3,
                         float* __restrict__ out3) {
    int r = blockIdx.x, c = threadIdx.x;   // c 0..63
    const float* arow = in2 + r * HDIM;
    float acc = (r == 65) ? b3[c] : 0.0f;
    for (int h = 0; h < HDIM; ++h)
        acc = fmaf(arow[h], W3[h * DDIM + c], acc);
    out3[r * DDIM + c] = acc;
}

// Packed 2xf32 FMA: acc.lo += a.lo*b.lo; acc.hi += a.hi*b.hi  (VOP3P, CDNA)
__device__ __forceinline__ void pkfma(f32x2& acc, f32x2 a, f32x2 b) {
    asm("v_pk_fma_f32 %0, %1, %2, %0" : "+v"(acc) : "v"(a), "v"(b));
}

// ---- Main scan: one wave per batch row, lane = output dim ----
//
// r13 lesson: 16-read drain (~12cyc/b128) + write->read turnaround dominate
// the 610cyc step. This round halves the DS drain: each lane reads only its
// OWN 32-half of the broadcast th-vector (8 b128) and computes partial dots
// for TWO columns (l&31 and (l&31)+32) over that half; lanes l and l^32
// then exchange complementary partials with ONE permlane32_swap (semantics
// self-calibrated at init, r8-proven). Also: s-recurrence
//   s_{k+1} = s_k + dt_k*wts + f_k*(Wscaled @ th_k)
// with params stored as (dt_k, f_k) — sc uses CURRENT prm, so the param
// prefetch + y-update + store all leave the serial chain.
__launch_bounds__(64, 1)
__global__ void fode_scan(const float* __restrict__ x, const float* __restrict__ t,
                          const float* __restrict__ Weff,   // 66 x 64 composed
                          float* __restrict__ out) {
    const int b = blockIdx.x;
    const int d = threadIdx.x;   // 0..63

    __shared__ __align__(16) float ylds[DDIM];
    __shared__ __align__(8) float2 plds[TSTEPS];  // (dt_k, factor_k); last unused

    const float invG = 0.56418958354775628695f;   // 1/Gamma(0.5)
    const float K2L = 2.88539008177792681472f;    // 2*log2(e)

    // Per-step params (dt, factor): coalesced staging, once per block.
    for (int i = d; i < TSTEPS - 1; i += DDIM) {
        float t0 = t[i];
        float t1 = t[i + 1];
        float dt = t1 - t0;
        plds[i] = make_float2(dt, sqrtf(dt) * invG);
    }

    const int lo = d & 31;
    const int hh = d >> 5;            // my half (0: j=0..31, 1: j=32..63)

    // Wa: column lo, Wb: column lo+32 — both over MY j-half, pre-scaled.
    f32x2 Wa[16], Wb[16];
#pragma unroll
    for (int c = 0; c < 16; ++c) {
        int j = 32 * hh + 2 * c;                  // row pair base (0-indexed j)
        Wa[c].x = K2L * Weff[(1 + j) * DDIM + lo];
        Wa[c].y = K2L * Weff[(2 + j) * DDIM + lo];
        Wb[c].x = K2L * Weff[(1 + j) * DDIM + lo + 32];
        Wb[c].y = K2L * Weff[(2 + j) * DDIM + lo + 32];
    }
    const float wts   = K2L * Weff[d];            // scaled t-coefficient (column d)
    const float biass = K2L * Weff[65 * DDIM + d];// scaled folded bias   (column d)

    // Calibrate permlane32_swap: probe with lane id; pick the output that
    // delivers lane d^32's value (robust to either swap semantic).
    auto cal = __builtin_amdgcn_permlane32_swap(d, d, false, false);
    const bool pick0 = (cal[0] == (d ^ 32));

    const unsigned ybase = (unsigned)(uintptr_t)&ylds[0];
    const unsigned waddr = ybase + 4u * (unsigned)d;
    const unsigned rbase = ybase + 128u * (unsigned)hh;   // my th half
    const unsigned pbase = (unsigned)(uintptr_t)&plds[0];

    const float t0g = t[0];

    float y = x[b * DDIM + d];
    float* op = out + (size_t)b * TSTEPS * DDIM + d;
    *op = y;                                      // solution[:,0,:] = x

#define READS8(r0,r1,r2,r3,r4,r5,r6,r7)                                   \
    asm volatile(                                                         \
        "ds_read_b128 %[o0], %[a] offset:0\n\t"                           \
        "ds_read_b128 %[o1], %[a] offset:16\n\t"                          \
        "ds_read_b128 %[o2], %[a] offset:32\n\t"                          \
        "ds_read_b128 %[o3], %[a] offset:48\n\t"                          \
        "ds_read_b128 %[o4], %[a] offset:64\n\t"                          \
        "ds_read_b128 %[o5], %[a] offset:80\n\t"                          \
        "ds_read_b128 %[o6], %[a] offset:96\n\t"                          \
        "ds_read_b128 %[o7], %[a] offset:112"                             \
        : [o0] "=&v"(r0), [o1] "=&v"(r1), [o2] "=&v"(r2), [o3] "=&v"(r3), \
          [o4] "=&v"(r4), [o5] "=&v"(r5), [o6] "=&v"(r6), [o7] "=&v"(r7)  \
        : [a] "v"(rbase))

#define QUADH(vq, c)                                                      \
    {                                                                     \
        f32x2 qlo = __builtin_shufflevector(vq, vq, 0, 1);                \
        f32x2 qhi = __builtin_shufflevector(vq, vq, 2, 3);                \
        pkfma(accA0, qlo, Wa[2 * (c) + 0]);                               \
        pkfma(accA1, qhi, Wa[2 * (c) + 1]);                               \
        pkfma(accB0, qlo, Wb[2 * (c) + 0]);                               \
        pkfma(accB1, qhi, Wb[2 * (c) + 1]);                               \
    }

    // ---- peel: s_0 = biass + t_0*wts + Wscaled @ y_0 ----
    float s;
    {
        asm volatile("ds_write_b32 %0, %1" :: "v"(waddr), "v"(y));
        f32x4 v0, v1, v2, v3, v4, v5, v6, v7;
        READS8(v0, v1, v2, v3, v4, v5, v6, v7);
        float base0 = fmaf(t0g, wts, biass);
        asm volatile("s_waitcnt lgkmcnt(0)" ::: "memory");  // staging+write+reads
        __builtin_amdgcn_sched_barrier(0);
        f32x2 accA0 = {0.f, 0.f}, accA1 = {0.f, 0.f};
        f32x2 accB0 = {0.f, 0.f}, accB1 = {0.f, 0.f};
        QUADH(v0, 0) QUADH(v1, 1) QUADH(v2, 2) QUADH(v3, 3)
        QUADH(v4, 4) QUADH(v5, 5) QUADH(v6, 6) QUADH(v7, 7)
        f32x2 ra = accA0 + accA1;  float qa = ra.x + ra.y;
        f32x2 rb = accB0 + accB1;  float qb = rb.x + rb.y;
        float keep = (d < 32) ? qa : qb;
        float send = (d < 32) ? qb : qa;
        auto sw = __builtin_amdgcn_permlane32_swap(__float_as_int(send),
                                                   __float_as_int(send), false, false);
        float recv = __int_as_float(pick0 ? sw[0] : sw[1]);
        s = base0 + (keep + recv);
    }

    f32x2 prm;                                    // (dt_k, f_k)
    prm.x = plds[0].x;
    prm.y = plds[0].y;

    for (int k = 0; k < TSTEPS - 1; ++k) {
        // ---- chain: tanh of s_k, broadcast th ----
        float e  = __builtin_amdgcn_exp2f(s);     // s pre-scaled by 2*log2(e)
        float th = fmaf(-2.0f, __builtin_amdgcn_rcpf(e + 1.0f), 1.0f);
        asm volatile("ds_write_b32 %0, %1" :: "v"(waddr), "v"(th));

        f32x4 v0, v1, v2, v3, v4, v5, v6, v7;
        READS8(v0, v1, v2, v3, v4, v5, v6, v7);
        f32x2 prmn;
        unsigned paddr = pbase + 8u * (unsigned)(k + 1);
        asm volatile("ds_read_b64 %0, %1" : "=&v"(prmn) : "v"(paddr));
        // Outstanding (oldest first): write, r0..r7, prmn  (10).

        // ---- off-chain while DS flies: y-update, store, sc ----
        y = fmaf(prm.y, th, y);                   // y_{k+1}
        op += DDIM;
        *op = y;                                  // fire-and-forget (vmcnt)
        float sc = fmaf(prm.x, wts, s);           // s_k + dt_k*wts

        f32x2 accA0 = {0.f, 0.f}, accA1 = {0.f, 0.f};
        f32x2 accB0 = {0.f, 0.f}, accB1 = {0.f, 0.f};

        asm volatile("s_waitcnt lgkmcnt(5)" ::: "memory");  // write+r0..r3 done
        __builtin_amdgcn_sched_barrier(0);
        QUADH(v0, 0) QUADH(v1, 1) QUADH(v2, 2) QUADH(v3, 3)

        asm volatile("s_waitcnt lgkmcnt(1)" ::: "memory");  // r4..r7 done
        __builtin_amdgcn_sched_barrier(0);
        QUADH(v4, 4) QUADH(v5, 5) QUADH(v6, 6) QUADH(v7, 7)

        // ---- combine: two half-dots -> full dot for column d ----
        f32x2 ra = accA0 + accA1;  float qa = ra.x + ra.y;
        f32x2 rb = accB0 + accB1;  float qb = rb.x + rb.y;
        float keep = (d < 32) ? qa : qb;
        float send = (d < 32) ? qb : qa;
        auto sw = __builtin_amdgcn_permlane32_swap(__float_as_int(send),
                                                   __float_as_int(send), false, false);
        float recv = __int_as_float(pick0 ? sw[0] : sw[1]);
        float dotT = keep + recv;

        s = fmaf(prm.y, dotT, sc);                // s_{k+1}

        asm volatile("s_waitcnt lgkmcnt(0)" ::: "memory");  // prmn arrived
        __builtin_amdgcn_sched_barrier(0);
        prm = prmn;
    }
#undef QUADH
#undef READS8
}

extern "C" void kernel_launch(void* const* d_in, const int* in_sizes, int n_in,
                              void* d_out, int out_size, void* d_ws, size_t ws_size,
                              hipStream_t stream) {
    const float* x  = (const float*)d_in[0];
    const float* t  = (const float*)d_in[1];
    const float* W0 = (const float*)d_in[2];
    const float* b0 = (const float*)d_in[3];
    const float* W1 = (const float*)d_in[4];
    const float* b1 = (const float*)d_in[5];
    const float* W2 = (const float*)d_in[6];
    const float* b2 = (const float*)d_in[7];
    const float* W3 = (const float*)d_in[8];
    const float* b3 = (const float*)d_in[9];
    float* out = (float*)d_out;

    float* buf1 = (float*)d_ws;            // 66*256 floats
    float* buf2 = buf1 + AROWS * HDIM;     // 66*256 floats
    float* buf3 = buf2 + AROWS * HDIM;     // 66*64 floats

    compose1<<<AROWS, HDIM, 0, stream>>>(W0, b0, W1, b1, buf1);
    compose2<<<AROWS, HDIM, 0, stream>>>(buf1, W2, b2, buf2);
    compose3<<<AROWS, DDIM, 0, stream>>>(buf2, W3, b3, buf3);
    fode_scan<<<BROWS, DDIM, 0, stream>>>(x, t, buf3, out);
}